// Round 5
// baseline (117.836 us; speedup 1.0000x reference)
//
#include <hip/hip_runtime.h>
#include <math.h>

// Problem constants (reference: N=256, S=1, stimulus 144x256, retina 144x256)
#define NB    256
#define IMG_H 144
#define IMG_W 256
#define IMG_ELEMS (IMG_H * IMG_W)   // 36864 floats
#define FDIM  16
#define DDIM  128

// Half-image LDS layout (zero-bordered), one (image, half) per block:
//   76 rows x 260-float stride = 79,040 B  -> 2 blocks/CU (158 KiB of 160)
//   TOP  (half=0): stored s = src_row+1, data rows 0..72 at s=1..73
//                  zero rows s=0,74,75; zero left group (offs 0..3) s=1..73
//   BOT  (half=1): stored s = src_row-71, data rows 72..143 at s=1..72
//                  zero rows s=0,73,74,75; zero left group s=1..72
//   data col c at offset c+4; x=-1 -> offset 3 (left zero group);
//   x=256,257 -> offsets 260,261 = next row's 0,1 (zeroed)
#define STRIDE 260
#define SROWS  76
#define SIMG_FLOATS (SROWS * STRIDE)   // 19760 floats = 79,040 B

#define FOV_HALF_RAD 0.6544984694978736f   // 0.5 * 75deg in rad
#define GELU_GAMMA   1.7015043497085571f

typedef float f32x4 __attribute__((ext_vector_type(4)));
typedef const __attribute__((address_space(1))) unsigned int glb_u32;
typedef __attribute__((address_space(3))) unsigned int lds_u32;

// jax.nn.gelu default is approximate=True (tanh form)
__device__ __forceinline__ float gelu_gamma(float x) {
    const float k0 = 0.7978845608028654f;  // sqrt(2/pi)
    const float k1 = 0.044715f;
    float t = tanhf(k0 * (x + k1 * x * x * x));
    return 0.5f * x * (1.0f + t) * GELU_GAMMA;
}

// 512 blocks = (image, source-half). Each block stages its half (79 KiB LDS)
// -> 2 blocks/CU, 32 waves/CU: cross-block overlap replaces the failed
// intra-block pipelining, and 8 waves/SIMD hide gather latency. Every thread
// runs the full per-pixel math (bit-identical to the verified r3 version) and
// stores only pixels whose 2x2 bilinear footprint lies in this block's half
// (yi<=71 / yi>=72: exact disjoint partition of all clamped yi in [-1,144]).
__global__ void __launch_bounds__(1024, 8) fused_retina_kernel(
    const float* __restrict__ stim,   // [NB, 1, IMG_H, IMG_W]
    const float* __restrict__ persp,  // [NB, FDIM]
    const float* __restrict__ W1,     // [FDIM, DDIM]
    const float* __restrict__ b1,     // [DDIM]
    const float* __restrict__ W2,     // [DDIM, DDIM]
    const float* __restrict__ b2,     // [DDIM]
    const float* __restrict__ Wp,     // [DDIM, 3]
    const float* __restrict__ bp,     // [3]
    float* __restrict__ out)          // [NB, 1, HR, WR]
{
    __shared__ float simg[SIMG_FLOATS];
    __shared__ float sh1[DDIM];
    __shared__ float sR[9];

    const int tid  = threadIdx.x;
    const int bid  = blockIdx.x;
    const int n    = bid >> 1;
    const int half = bid & 1;
    const int wid  = tid >> 6;
    const int lane = tid & 63;

    const float* __restrict__ img = stim + (size_t)n * IMG_ELEMS;

    // ---- zero the border cells (f32x4 groups, disjoint from staged data)
    {
        const int nzr = half ? 4 : 3;          // full zero rows
        f32x4 z = {0.0f, 0.0f, 0.0f, 0.0f};
        if (tid < nzr * 65) {
            const int zi = tid / 65;
            const int g  = tid - zi * 65;      // 0..64 -> offsets 0..259
            int row;
            if (half) row = (zi == 0) ? 0 : (72 + zi);   // 0,73,74,75
            else      row = (zi == 0) ? 0 : (73 + zi);   // 0,74,75
            *(f32x4*)&simg[row * STRIDE + g * 4] = z;
        } else {
            const int t     = tid - nzr * 65;
            const int nleft = half ? 72 : 73;  // left groups of data rows
            if (t < nleft)
                *(f32x4*)&simg[(t + 1) * STRIDE] = z;
        }
    }

    const int row0  = half ? 72 : 0;           // first staged source row
    const int nrows = half ? 72 : 73;          // staged source rows

    if (wid > 0) {
        // ---- waves 1..15: async stage, one image row per wave-issue.
        // 64 lanes x 16B = 1024B = one 256-float row; LDS dest = uniform
        // base + lane*16 (hardware), global src = per-lane address.
        const int v = wid - 1;                 // 0..14
#pragma unroll
        for (int p = 0; p < 5; ++p) {
            const int j = v + 15 * p;          // 0..74
            if (j < nrows) {
                const float* gsrc = img + (size_t)(row0 + j) * IMG_W + lane * 4;
                float* ldst = &simg[(j + 1) * STRIDE + 4];
                __builtin_amdgcn_global_load_lds(
                    (glb_u32*)gsrc, (lds_u32*)ldst, 16, 0, 0);
            }
        }
    } else {
        // ---- wave 0: MLP (single-wave; lgkmcnt orders LDS within the wave)
        float a0 = b1[lane], a1 = b1[lane + 64];
#pragma unroll
        for (int f = 0; f < FDIM; ++f) {
            const float p = persp[n * FDIM + f];
            a0 = fmaf(p, W1[f * DDIM + lane],      a0);
            a1 = fmaf(p, W1[f * DDIM + lane + 64], a1);
        }
        sh1[lane]      = gelu_gamma(a0);
        sh1[lane + 64] = gelu_gamma(a1);
        asm volatile("s_waitcnt lgkmcnt(0)" ::: "memory");

        float c0 = b2[lane], c1 = b2[lane + 64];
#pragma unroll 8
        for (int k = 0; k < DDIM; ++k) {
            const float s = sh1[k];
            c0 = fmaf(s, W2[k * DDIM + lane],      c0);
            c1 = fmaf(s, W2[k * DDIM + lane + 64], c1);
        }
        const float g0 = gelu_gamma(c0);       // = h2[lane]
        const float g1 = gelu_gamma(c1);       // = h2[lane+64]

        // layer 3 wave-parallel: ang_j = sum_k h2[k]*Wp[k*3+j] + bp[j]
        float p0 = fmaf(g0, Wp[lane * 3 + 0], g1 * Wp[(lane + 64) * 3 + 0]);
        float p1 = fmaf(g0, Wp[lane * 3 + 1], g1 * Wp[(lane + 64) * 3 + 1]);
        float p2 = fmaf(g0, Wp[lane * 3 + 2], g1 * Wp[(lane + 64) * 3 + 2]);
#pragma unroll
        for (int m = 32; m >= 1; m >>= 1) {
            p0 += __shfl_xor(p0, m);
            p1 += __shfl_xor(p1, m);
            p2 += __shfl_xor(p2, m);
        }

        if (lane == 0) {
            const float ax = p0 + bp[0], ay = p1 + bp[1], az = p2 + bp[2];
            const float cx = cosf(ax), sx = sinf(ax);
            const float cy = cosf(ay), sy = sinf(ay);
            const float cz = cosf(az), sz = sinf(az);
            sR[0] = cz * cy;  sR[1] = cz * sy * sx - sz * cx;  sR[2] = cz * sy * cx + sz * sx;
            sR[3] = sz * cy;  sR[4] = sz * sy * sx + cz * cx;  sR[5] = sz * sy * cx - cz * sx;
            sR[6] = -sy;      sR[7] = cy * sx;                 sR[8] = cy * cx;
        }
    }
    __syncthreads();   // drains vmcnt (stage) + lgkmcnt everywhere

    // block-uniform rotation (LDS broadcast reads, conflict-free)
    const float r0 = sR[0], r1 = sR[1], r2 = sR[2];
    const float r3 = sR[3], r4 = sR[4], r5 = sR[5];
    const float r6 = sR[6], r7 = sR[7], r8 = sR[8];

    float* __restrict__ outn = out + (size_t)n * IMG_ELEMS;

    // per-thread (column) constants
    const int w     = tid & 255;           // output column: iteration-invariant
    const int hbase = tid >> 8;            // 0..3
    const float gx  = ((float)(2 * w + 1) - 256.0f) * (1.0f / 256.0f);
    const float axv = gx * FOV_HALF_RAD;
    const float ax2 = axv * axv;
    const float A0 = r0 * axv, A1 = r3 * axv, A2 = r6 * axv;
    const int sb = half ? 71 : -1;         // s = yi - sb

#pragma unroll 4
    for (int it = 0; it < 36; ++it) {
        const int h   = it * 4 + hbase;
        const int px0 = (h << 8) | w;

        const float gy  = ((float)(2 * h + 1) - 144.0f) * (1.0f / 256.0f);
        const float ayv = gy * FOV_HALF_RAD;
        const float tt  = fmaf(ayv, ayv, ax2);   // a^2 <= 0.56

        // sinc(a): even Taylor in t, |err| ~1e-8 on this range
        float sc = fmaf(tt, 2.7557319e-6f, -1.9841270e-4f);
        sc = fmaf(tt, sc,  8.3333333e-3f);
        sc = fmaf(tt, sc, -1.6666667e-1f);
        sc = fmaf(tt, sc,  1.0f);

        // cos(a): even Taylor in t
        float ca = fmaf(tt, 2.4801587e-5f, -1.3888889e-3f);
        ca = fmaf(tt, ca,  4.1666667e-2f);
        ca = fmaf(tt, ca, -0.5f);
        ca = fmaf(tt, ca,  1.0f);

        // rotated ray: r_i = sc*(R_i0*ax + R_i1*ay) + R_i2*ca
        const float rx = fmaf(sc, fmaf(r1, ayv, A0), r2 * ca);
        const float ry = fmaf(sc, fmaf(r4, ayv, A1), r5 * ca);
        const float rz = fmaf(sc, fmaf(r7, ayv, A2), r8 * ca);

        const float inv  = __builtin_amdgcn_rcpf(rz);
        const float s128 = 128.0f * inv;         // fold *256 and *0.5
        const bool  safe = rz > 0.001f;

        float pxf = fmaf(rx, s128, 127.5f);
        float pyf = fmaf(ry, s128, 71.5f);
        pxf = safe ? pxf : 300.0f;               // out-of-range -> border clamp
        pyf = safe ? pyf : 300.0f;
        // clamp onto the zero border: out-of-range lands on zero cells with
        // zero fractional weight -> exact per-corner mask semantics
        pxf = fminf(fmaxf(pxf, -1.0f), 256.0f);
        pyf = fminf(fmaxf(pyf, -1.0f), 144.0f);

        const float x0f = floorf(pxf), y0f = floorf(pyf);
        const float wx  = pxf - x0f,   wy  = pyf - y0f;
        const int   xi  = (int)x0f,    yi  = (int)y0f;   // xi in [-1,256], yi in [-1,144]

        // ownership: top block owns yi<=71, bottom owns yi>=72 (disjoint)
        const bool mine = half ? (yi >= 72) : (yi <= 71);
        const int  a00  = mine ? ((yi - sb) * STRIDE + xi + 4) : 4;
        const int  a10  = a00 + STRIDE;

        const float v00 = simg[a00];
        const float v01 = simg[a00 + 1];
        const float v10 = simg[a10];
        const float v11 = simg[a10 + 1];

        const float top = fmaf(wx, v01 - v00, v00);
        const float bot = fmaf(wx, v11 - v10, v10);
        const float res = fmaf(wy, bot - top, top);

        if (mine)
            __builtin_nontemporal_store(res, outn + px0);
    }
}

extern "C" void kernel_launch(void* const* d_in, const int* in_sizes, int n_in,
                              void* d_out, int out_size, void* d_ws, size_t ws_size,
                              hipStream_t stream) {
    const float* stimulus    = (const float*)d_in[0]; // [256,1,144,256]
    const float* perspective = (const float*)d_in[1]; // [256,16]
    const float* W1          = (const float*)d_in[2]; // [16,128]
    const float* b1          = (const float*)d_in[3]; // [128]
    const float* W2          = (const float*)d_in[4]; // [128,128]
    const float* b2          = (const float*)d_in[5]; // [128]
    const float* Wp          = (const float*)d_in[6]; // [128,3]
    const float* bp          = (const float*)d_in[7]; // [3]
    float* out = (float*)d_out;

    (void)d_ws; (void)ws_size;

    fused_retina_kernel<<<NB * 2, 1024, 0, stream>>>(
        stimulus, perspective, W1, b1, W2, b2, Wp, bp, out);
}

// Round 6
// 117.028 us; speedup vs baseline: 1.0069x; 1.0069x over previous
//
#include <hip/hip_runtime.h>
#include <math.h>

// Problem constants (reference: N=256, S=1, stimulus 144x256, retina 144x256)
#define NB    256
#define IMG_H 144
#define IMG_W 256
#define IMG_ELEMS (IMG_H * IMG_W)   // 36864 floats
#define HR    144
#define WR    256
#define FDIM  16
#define DDIM  128

// LDS image layout: zero-bordered.
//   stored row s = src_row + 1, s in [0,146]; row stride 260 floats (1040 B, 16B aligned)
//   data col c at offset c+4 (offsets 4..259); offset 3 = left zero border (x=-1)
//   offsets 260,261 of a row = offsets 0,1 of next row (right border x=256,257) -> zeroed
//   rows s=0 (y=-1), s=145 (y=144), s=146 (y=145) fully zero; tail group at 147*260
#define STRIDE 260
#define SIMG_FLOATS (147 * STRIDE + 4)   // 38224 floats = 149.3 KiB

#define FOV_HALF_RAD 0.6544984694978736f   // 0.5 * 75deg in rad
#define GELU_GAMMA   1.7015043497085571f
#define OUT_OF_RANGE 10.0f

typedef float f32x4 __attribute__((ext_vector_type(4)));

// jax.nn.gelu default is approximate=True (tanh form)
__device__ __forceinline__ float gelu_gamma(float x) {
    const float k0 = 0.7978845608028654f;  // sqrt(2/pi)
    const float k1 = 0.044715f;
    float t = tanhf(k0 * (x + k1 * x * x * x));
    return 0.5f * x * (1.0f + t) * GELU_GAMMA;
}

// Fully fused: per-image MLP -> rotation matrix -> retina resample.
// One block per image, 1024 threads. Wave 0 runs the MLP (single-wave, no
// block barriers needed) while waves 1..15 stage the image into LDS. d_ws is
// NOT used. This is the best-measured configuration of the session (114.21us);
// kernel-side improvements below the ~42us poison-fill horizon are invisible
// in dur_us (r3 null, r4 +1.3, r5 +3.5): dur is pinned by the harness's
// 2x256MiB unconditional poison fills overlapping our 75MB of kernel traffic.
__global__ void __launch_bounds__(1024, 4) fused_retina_kernel(
    const float* __restrict__ stim,   // [NB, 1, IMG_H, IMG_W]
    const float* __restrict__ persp,  // [NB, FDIM]
    const float* __restrict__ W1,     // [FDIM, DDIM]
    const float* __restrict__ b1,     // [DDIM]
    const float* __restrict__ W2,     // [DDIM, DDIM]
    const float* __restrict__ b2,     // [DDIM]
    const float* __restrict__ Wp,     // [DDIM, 3]
    const float* __restrict__ bp,     // [3]
    float* __restrict__ out)          // [NB, 1, HR, WR]
{
    __shared__ float simg[SIMG_FLOATS];
    __shared__ float sh1[DDIM];
    __shared__ float sh2[DDIM];
    __shared__ float sAng[3];
    __shared__ float sR[9];

    const int tid  = threadIdx.x;
    const int n    = blockIdx.x;
    const int wid  = tid >> 6;
    const int lane = tid & 63;

    const float* __restrict__ img = stim + (size_t)n * IMG_ELEMS;

    // ---- zero the border cells (340 f32x4 groups, disjoint from staged data)
    if (tid < 340) {
        f32x4 z = {0.0f, 0.0f, 0.0f, 0.0f};
        int idx;
        if (tid < 195) {                       // full zero rows s=0,145,146
            const int rr = tid / 65;
            const int g  = tid - rr * 65;      // 0..64 -> offsets 0..259
            const int s  = (rr == 0) ? 0 : (144 + rr);
            idx = s * STRIDE + g * 4;
        } else if (tid < 339) {                // left borders of data rows s=1..144
            idx = (tid - 194) * STRIDE;        // offsets 0..3
        } else {                               // tail cells after row s=146
            idx = 147 * STRIDE;                // 38220..38223
        }
        *(f32x4*)&simg[idx] = z;
    }

    if (wid > 0) {
        // ---- waves 1..15: stage image -> LDS (9216 f32x4 groups over 960 threads)
        const int t = tid - 64;
        const f32x4* __restrict__ src = (const f32x4*)img;
#pragma unroll
        for (int p = 0; p < 10; ++p) {
            const int g = t + p * 960;
            if (g < 9216) {
                const int row = g >> 6;        // 64 groups per image row
                const int c4  = g & 63;
                *(f32x4*)&simg[(row + 1) * STRIDE + 4 + c4 * 4] = src[g];
            }
        }
    } else {
        // ---- wave 0: the whole MLP, single-wave (lgkmcnt orders LDS within wave)
        float a0 = b1[lane], a1 = b1[lane + 64];
#pragma unroll
        for (int f = 0; f < FDIM; ++f) {
            const float p = persp[n * FDIM + f];
            a0 = fmaf(p, W1[f * DDIM + lane],      a0);
            a1 = fmaf(p, W1[f * DDIM + lane + 64], a1);
        }
        sh1[lane]      = gelu_gamma(a0);
        sh1[lane + 64] = gelu_gamma(a1);
        asm volatile("s_waitcnt lgkmcnt(0)" ::: "memory");

        float c0 = b2[lane], c1 = b2[lane + 64];
#pragma unroll 8
        for (int k = 0; k < DDIM; ++k) {
            const float s = sh1[k];
            c0 = fmaf(s, W2[k * DDIM + lane],      c0);
            c1 = fmaf(s, W2[k * DDIM + lane + 64], c1);
        }
        sh2[lane]      = gelu_gamma(c0);
        sh2[lane + 64] = gelu_gamma(c1);
        asm volatile("s_waitcnt lgkmcnt(0)" ::: "memory");

        if (lane < 3) {
            float a = bp[lane];
#pragma unroll 8
            for (int k = 0; k < DDIM; ++k)
                a = fmaf(sh2[k], Wp[k * 3 + lane], a);
            sAng[lane] = a;
        }
        asm volatile("s_waitcnt lgkmcnt(0)" ::: "memory");

        if (lane == 0) {
            const float cx = cosf(sAng[0]), sx = sinf(sAng[0]);
            const float cy = cosf(sAng[1]), sy = sinf(sAng[1]);
            const float cz = cosf(sAng[2]), sz = sinf(sAng[2]);
            sR[0] = cz * cy;  sR[1] = cz * sy * sx - sz * cx;  sR[2] = cz * sy * cx + sz * sx;
            sR[3] = sz * cy;  sR[4] = sz * sy * sx + cz * cx;  sR[5] = sz * sy * cx - cz * sx;
            sR[6] = -sy;      sR[7] = cy * sx;                 sR[8] = cy * cx;
        }
    }
    __syncthreads();

    // block-uniform rotation (LDS broadcast reads, conflict-free)
    const float r0 = sR[0], r1 = sR[1], r2 = sR[2];
    const float r3 = sR[3], r4 = sR[4], r5 = sR[5];
    const float r6 = sR[6], r7 = sR[7], r8 = sR[8];

    float* __restrict__ outn = out + (size_t)n * IMG_ELEMS;

    // ---- gather: lane-adjacent pixels (source lane-stride ~1 dword -> ~no
    // bank conflicts); zero border removes all masks/clamps; v00/v01 and
    // v10/v11 adjacent -> ds_read2_b32 pairs
#pragma unroll 4
    for (int it = 0; it < 36; ++it) {
        const int px0 = it * 1024 + tid;
        const int h   = px0 >> 8;
        const int w   = px0 & 255;

        const float gx  = ((float)(2 * w + 1) - 256.0f) * (1.0f / 256.0f);
        const float gy  = ((float)(2 * h + 1) - 144.0f) * (1.0f / 256.0f);
        const float axv = gx * FOV_HALF_RAD;
        const float ayv = gy * FOV_HALF_RAD;
        const float tt  = fmaf(axv, axv, ayv * ayv);   // a^2 <= 0.56

        // sinc(a): even Taylor in t, |err| ~1e-8 on this range
        float sc = fmaf(tt, 2.7557319e-6f, -1.9841270e-4f);
        sc = fmaf(tt, sc,  8.3333333e-3f);
        sc = fmaf(tt, sc, -1.6666667e-1f);
        sc = fmaf(tt, sc,  1.0f);

        // cos(a): even Taylor in t
        float ca = fmaf(tt, 2.4801587e-5f, -1.3888889e-3f);
        ca = fmaf(tt, ca,  4.1666667e-2f);
        ca = fmaf(tt, ca, -0.5f);
        ca = fmaf(tt, ca,  1.0f);

        const float dx = sc * axv, dy = sc * ayv, dz = ca;

        const float rx = fmaf(r0, dx, fmaf(r1, dy, r2 * dz));
        const float ry = fmaf(r3, dx, fmaf(r4, dy, r5 * dz));
        const float rz = fmaf(r6, dx, fmaf(r7, dy, r8 * dz));

        const float inv  = __builtin_amdgcn_rcpf(rz);
        const bool  safe = rz > 0.001f;
        const float gxp  = safe ? rx * inv : OUT_OF_RANGE;
        const float gyp  = safe ? ry * inv : OUT_OF_RANGE;

        float pxf = fmaf(gxp, 256.0f, (float)(IMG_W - 1)) * 0.5f;
        float pyf = fmaf(gyp, 256.0f, (float)(IMG_H - 1)) * 0.5f;
        // clamp onto the zero border: out-of-range lands on zero cells with
        // zero fractional weight -> exact per-corner mask semantics
        pxf = fminf(fmaxf(pxf, -1.0f), 256.0f);
        pyf = fminf(fmaxf(pyf, -1.0f), 144.0f);

        const float x0f = floorf(pxf), y0f = floorf(pyf);
        const float wx  = pxf - x0f,   wy  = pyf - y0f;
        const int   xi  = (int)x0f,    yi  = (int)y0f;   // xi in [-1,256], yi in [-1,144]

        const int a00 = (yi + 1) * STRIDE + xi + 4;
        const int a10 = a00 + STRIDE;

        const float v00 = simg[a00];
        const float v01 = simg[a00 + 1];
        const float v10 = simg[a10];
        const float v11 = simg[a10 + 1];

        const float top = fmaf(wx, v01 - v00, v00);
        const float bot = fmaf(wx, v11 - v10, v10);
        const float res = fmaf(wy, bot - top, top);

        __builtin_nontemporal_store(res, outn + px0);
    }
}

extern "C" void kernel_launch(void* const* d_in, const int* in_sizes, int n_in,
                              void* d_out, int out_size, void* d_ws, size_t ws_size,
                              hipStream_t stream) {
    const float* stimulus    = (const float*)d_in[0]; // [256,1,144,256]
    const float* perspective = (const float*)d_in[1]; // [256,16]
    const float* W1          = (const float*)d_in[2]; // [16,128]
    const float* b1          = (const float*)d_in[3]; // [128]
    const float* W2          = (const float*)d_in[4]; // [128,128]
    const float* b2          = (const float*)d_in[5]; // [128]
    const float* Wp          = (const float*)d_in[6]; // [128,3]
    const float* bp          = (const float*)d_in[7]; // [3]
    float* out = (float*)d_out;

    (void)d_ws; (void)ws_size;  // intentionally unused: workspace poison is unconditional

    fused_retina_kernel<<<NB, 1024, 0, stream>>>(
        stimulus, perspective, W1, b1, W2, b2, Wp, bp, out);
}